// Round 1
// baseline (649.521 us; speedup 1.0000x reference)
//
#include <hip/hip_runtime.h>
#include <math.h>

#define TT 2000
#define BB 32
#define VV 1000
#define SS 200
#define LROW 256   // floats per PL row: [0,200) = p(target labels), rest 0

#if defined(__has_builtin) && __has_builtin(__builtin_amdgcn_ldexpf)
__device__ __forceinline__ float ldx(float x, int e) { return __builtin_amdgcn_ldexpf(x, e); }
#else
__device__ __forceinline__ float ldx(float x, int e) { return ldexpf(x, e); }
#endif

// ---------------- Phase 1: softmax rows + gather needed probs ----------------
// One wave per (t,b) row of 1000 logits. Writes PL[row][256] (label probs) and
// PB[row] (blank prob). Memory-bound: 256 MB read + 66 MB write.
__global__ __launch_bounds__(256) void ctc_phase1(
    const float* __restrict__ logits, const int* __restrict__ targets,
    float* __restrict__ PL, float* __restrict__ PB, float* __restrict__ out)
{
    if (blockIdx.x == 0 && threadIdx.x == 0) out[0] = 0.f;  // zero accumulator for phase2 atomics
    int wid  = (blockIdx.x * 256 + threadIdx.x) >> 6;       // row id = t*BB + b
    int lane = threadIdx.x & 63;
    if (wid >= TT * BB) return;
    const float* __restrict__ row = logits + (size_t)wid * VV;
    int b = wid & (BB - 1);

    // 16 floats/lane, strided float4 loads (coalesced 1KB/instr). 1000 % 4 == 0
    // so each float4 is fully valid or fully OOB (only k=3, lanes >= 58).
    int i0 = 4 * lane;
    float4 v0 = *(const float4*)(row + i0);
    float4 v1 = *(const float4*)(row + i0 + 256);
    float4 v2 = *(const float4*)(row + i0 + 512);
    int i3 = i0 + 768;
    float4 v3 = *(const float4*)(row + (i3 < VV ? i3 : 0));
    if (i3 >= VV) { v3.x = v3.y = v3.z = v3.w = -1e30f; }

    float M = fmaxf(fmaxf(fmaxf(v0.x, v0.y), fmaxf(v0.z, v0.w)),
                    fmaxf(fmaxf(fmaxf(v1.x, v1.y), fmaxf(v1.z, v1.w)),
                          fmaxf(fmaxf(fmaxf(v2.x, v2.y), fmaxf(v2.z, v2.w)),
                                fmaxf(fmaxf(v3.x, v3.y), fmaxf(v3.z, v3.w)))));
    #pragma unroll
    for (int off = 1; off < 64; off <<= 1) M = fmaxf(M, __shfl_xor(M, off));

    float s = __expf(v0.x - M) + __expf(v0.y - M) + __expf(v0.z - M) + __expf(v0.w - M)
            + __expf(v1.x - M) + __expf(v1.y - M) + __expf(v1.z - M) + __expf(v1.w - M)
            + __expf(v2.x - M) + __expf(v2.y - M) + __expf(v2.z - M) + __expf(v2.w - M)
            + __expf(v3.x - M) + __expf(v3.y - M) + __expf(v3.z - M) + __expf(v3.w - M);
    #pragma unroll
    for (int off = 1; off < 64; off <<= 1) s += __shfl_xor(s, off);
    float inv = 1.0f / s;

    const int* __restrict__ tg = targets + b * SS;
    #pragma unroll
    for (int k = 0; k < 4; k++) {
        int j = k * 64 + lane;
        int lbl = (j < SS) ? tg[j] : 0;
        float g = row[lbl];                          // gather; row is L1/L2-hot
        float pv = (j < SS) ? (__expf(g - M) * inv) : 0.f;
        PL[(size_t)wid * LROW + j] = pv;
    }
    if (lane == 0) PB[wid] = __expf(row[0] - M) * inv;
}

// ---------------- Phase 2: CTC forward recursion ----------------
// One 64-lane wave per batch element. Lane l holds ext-lattice states
// 8l..8l+7 (L = 401 real states, rest padding with p=0 -> stay 0).
// Linear domain with per-lane power-of-2 scaling (exact, via v_ldexp).
// Even states (blank): a' = (a + s1)*pb ; odd: a' = (a + s1 + m*s2)*pl.
// Only cross-lane value needed per step: prev lane's a7.

#define STEP(q, qb) do {                                    \
    float sh_  = __shfl_up(a7, 1);                          \
    float prev = ldx(sh_, dB);            /* lane0: dB=-100000 -> 0 */ \
    float n0 = (a0 + prev) * (qb);                          \
    float n1 = fmaf(mk0, prev, a1 + a0) * (q).x;            \
    float n2 = (a2 + a1) * (qb);                            \
    float n3 = fmaf(mk1, a1, a3 + a2) * (q).y;              \
    float n4 = (a4 + a3) * (qb);                            \
    float n5 = fmaf(mk2, a3, a5 + a4) * (q).z;              \
    float n6 = (a6 + a5) * (qb);                            \
    float n7 = fmaf(mk3, a5, a7 + a6) * (q).w;              \
    a0=n0; a1=n1; a2=n2; a3=n3; a4=n4; a5=n5; a6=n6; a7=n7; } while (0)

#define RESCALE() do {                                      \
    float mx = fmaxf(fmaxf(fmaxf(a0,a1),fmaxf(a2,a3)),fmaxf(fmaxf(a4,a5),fmaxf(a6,a7))); \
    unsigned eb = (__float_as_uint(mx) >> 23) & 255u;       \
    int de = (eb == 0u) ? 0 : ((int)eb - 127);              \
    a0 = ldx(a0, -de); a1 = ldx(a1, -de); a2 = ldx(a2, -de); a3 = ldx(a3, -de); \
    a4 = ldx(a4, -de); a5 = ldx(a5, -de); a6 = ldx(a6, -de); a7 = ldx(a7, -de); \
    e_acc += de;                                            \
    int she = __shfl_up(e_acc, 1);                          \
    if (eb == 0u) e_acc = she;        /* inactive lane adopts prev's scale */ \
    dB = (lane == 0) ? -100000 : (she - e_acc); } while (0)

#define LOADG(PLb, PBb, basestep) do {                      \
    _Pragma("unroll")                                       \
    for (int k_ = 0; k_ < 16; k_++) {                       \
        int t_ = (basestep) + k_ + 1;                       \
        t_ = (t_ < Tb) ? t_ : (Tb - 1);                     \
        const float4* rp_ = (const float4*)(PL + ((size_t)t_ * BB + b) * LROW); \
        PLb[k_] = rp_[lane];                                \
        PBb[k_] = PB[t_ * BB + b];                          \
    } } while (0)

__global__ __launch_bounds__(64, 1) void ctc_phase2(
    const float* __restrict__ PL, const float* __restrict__ PB,
    const int* __restrict__ targets, const int* __restrict__ ilen,
    const int* __restrict__ tlen, float* __restrict__ out)
{
    int b = blockIdx.x;
    int lane = threadIdx.x;
    const int* __restrict__ tg = targets + b * SS;

    // skip masks for odd states s=8l+2c+1 (u=(s-1)/2=4l+c): s>=3 && u>=1 && tg[u]!=tg[u-1]
    float mk0 = 0.f, mk1 = 0.f, mk2 = 0.f, mk3 = 0.f;
    {
        int u0 = 4 * lane;
        if (u0 >= 1 && u0 < SS) mk0 = (tg[u0] != tg[u0 - 1]) ? 1.f : 0.f;
        if (u0 + 1 < SS)        mk1 = (tg[u0 + 1] != tg[u0]) ? 1.f : 0.f;
        if (u0 + 2 < SS)        mk2 = (tg[u0 + 2] != tg[u0 + 1]) ? 1.f : 0.f;
        if (u0 + 3 < SS)        mk3 = (tg[u0 + 3] != tg[u0 + 2]) ? 1.f : 0.f;
    }
    int Tb = ilen[b];
    int tl = tlen[b];

    float a0=0,a1=0,a2=0,a3=0,a4=0,a5=0,a6=0,a7=0;
    int e_acc = 0;
    int dB = (lane == 0) ? -100000 : 0;

    // t = 0 init: alpha[0] = p_blank, alpha[1] = p(tgt[0])
    {
        const float4* r0 = (const float4*)(PL + (size_t)b * LROW);
        float4 p0 = r0[lane];
        float pb0 = PB[b];
        if (lane == 0) { a0 = pb0; a1 = p0.x; }
    }

    int nsteps = Tb - 1;
    float4 plA[16]; float pbA[16];
    float4 plB[16]; float pbB[16];

    LOADG(plA, pbA, 0);
    int s = 0;
    for (; s + 32 <= nsteps; s += 32) {
        LOADG(plB, pbB, s + 16);
        #pragma unroll
        for (int k = 0; k < 16; k++) { STEP(plA[k], pbA[k]); if ((k & 3) == 3) RESCALE(); }
        LOADG(plA, pbA, s + 32);
        #pragma unroll
        for (int k = 0; k < 16; k++) { STEP(plB[k], pbB[k]); if ((k & 3) == 3) RESCALE(); }
    }
    int rem = nsteps - s;                 // < 32; bank A already holds [s, s+16)
    int r1 = rem < 16 ? rem : 16;
    #pragma unroll
    for (int k = 0; k < 16; k++) { if (k < r1) { STEP(plA[k], pbA[k]); if ((k & 3) == 3) RESCALE(); } }
    if (rem > 16) {
        LOADG(plB, pbB, s + 16);
        int r2 = rem - 16;
        #pragma unroll
        for (int k = 0; k < 16; k++) { if (k < r2) { STEP(plB[k], pbB[k]); if ((k & 3) == 3) RESCALE(); } }
    }

    // readout: loss = -logaddexp(alpha[2*tl], alpha[2*tl-1])
    __shared__ float sa[64][8];
    __shared__ int   se[64];
    sa[lane][0]=a0; sa[lane][1]=a1; sa[lane][2]=a2; sa[lane][3]=a3;
    sa[lane][4]=a4; sa[lane][5]=a5; sa[lane][6]=a6; sa[lane][7]=a7;
    se[lane] = e_acc;
    __syncthreads();
    if (lane == 0) {
        int end = 2 * tl;
        float ae = sa[end >> 3][end & 7];
        float am = sa[(end - 1) >> 3][(end - 1) & 7];
        int   ee = se[end >> 3];
        int   em = se[(end - 1) >> 3];
        float val = ae + ldx(am, em - ee);           // bring to common scale
        double lb = -((double)logf(val) + (double)ee * 0.6931471805599453);
        float contrib = (float)(lb / ((double)tl * (double)BB));
        atomicAdd(out, contrib);
    }
}

extern "C" void kernel_launch(void* const* d_in, const int* in_sizes, int n_in,
                              void* d_out, int out_size, void* d_ws, size_t ws_size,
                              hipStream_t stream)
{
    const float* logits  = (const float*)d_in[0];
    const int*   targets = (const int*)d_in[1];
    const int*   ilen    = (const int*)d_in[2];
    const int*   tlen    = (const int*)d_in[3];
    float* out = (float*)d_out;

    float* PL = (float*)d_ws;                                  // [TT*BB][256] f32
    float* PB = PL + (size_t)TT * BB * LROW;                   // [TT*BB] f32

    ctc_phase1<<<(TT * BB) / 4, 256, 0, stream>>>(logits, targets, PL, PB, out);
    ctc_phase2<<<BB, 64, 0, stream>>>(PL, PB, targets, ilen, tlen, out);
}

// Round 3
// 595.821 us; speedup vs baseline: 1.0901x; 1.0901x over previous
//
#include <hip/hip_runtime.h>
#include <math.h>

#define TT 2000
#define BB 32
#define VV 1000
#define SS 200
#define LROW 256   // floats per PL row: [0,200)=p(labels), [200]=p(blank), rest 0

__device__ __forceinline__ float ldx(float x, int e) { return ldexpf(x, e); }

// ---------------- Phase 1: softmax rows + gather needed probs ----------------
// One wave per (t,b) row of 1000 logits. Writes PL[row][256] and PB[row].
__global__ __launch_bounds__(256) void ctc_phase1(
    const float* __restrict__ logits, const int* __restrict__ targets,
    float* __restrict__ PL, float* __restrict__ PB, float* __restrict__ out)
{
    if (blockIdx.x == 0 && threadIdx.x == 0) out[0] = 0.f;  // zero accumulator for phase2 atomics
    int wid  = (blockIdx.x * 256 + threadIdx.x) >> 6;       // row id = t*BB + b
    int lane = threadIdx.x & 63;
    if (wid >= TT * BB) return;
    const float* __restrict__ row = logits + (size_t)wid * VV;
    int b = wid & (BB - 1);

    // 16 floats/lane, strided float4 loads (coalesced 1KB/instr). 1000 % 4 == 0.
    int i0 = 4 * lane;
    float4 v0 = *(const float4*)(row + i0);
    float4 v1 = *(const float4*)(row + i0 + 256);
    float4 v2 = *(const float4*)(row + i0 + 512);
    int i3 = i0 + 768;
    float4 v3 = *(const float4*)(row + (i3 < VV ? i3 : 0));
    if (i3 >= VV) { v3.x = v3.y = v3.z = v3.w = -1e30f; }

    float M = fmaxf(fmaxf(fmaxf(v0.x, v0.y), fmaxf(v0.z, v0.w)),
                    fmaxf(fmaxf(fmaxf(v1.x, v1.y), fmaxf(v1.z, v1.w)),
                          fmaxf(fmaxf(fmaxf(v2.x, v2.y), fmaxf(v2.z, v2.w)),
                                fmaxf(fmaxf(v3.x, v3.y), fmaxf(v3.z, v3.w)))));
    #pragma unroll
    for (int off = 1; off < 64; off <<= 1) M = fmaxf(M, __shfl_xor(M, off));

    float s = __expf(v0.x - M) + __expf(v0.y - M) + __expf(v0.z - M) + __expf(v0.w - M)
            + __expf(v1.x - M) + __expf(v1.y - M) + __expf(v1.z - M) + __expf(v1.w - M)
            + __expf(v2.x - M) + __expf(v2.y - M) + __expf(v2.z - M) + __expf(v2.w - M)
            + __expf(v3.x - M) + __expf(v3.y - M) + __expf(v3.z - M) + __expf(v3.w - M);
    #pragma unroll
    for (int off = 1; off < 64; off <<= 1) s += __shfl_xor(s, off);
    float inv = 1.0f / s;

    const int* __restrict__ tg = targets + b * SS;
    int j0 = 4 * lane;
    int4 tt = ((const int4*)tg)[(j0 < SS) ? lane : 0];   // guarded vs OOB at b=31
    int l0 = (j0     < SS) ? tt.x : 0;
    int l1 = (j0 + 1 < SS) ? tt.y : 0;
    int l2 = (j0 + 2 < SS) ? tt.z : 0;
    int l3 = (j0 + 3 < SS) ? tt.w : 0;
    // j<SS -> label prob; j==SS -> blank prob (l=0); j>SS -> 0
    float4 w;
    w.x = (j0     <= SS) ? (__expf(row[l0] - M) * inv) : 0.f;
    w.y = (j0 + 1 <= SS) ? (__expf(row[l1] - M) * inv) : 0.f;
    w.z = (j0 + 2 <= SS) ? (__expf(row[l2] - M) * inv) : 0.f;
    w.w = (j0 + 3 <= SS) ? (__expf(row[l3] - M) * inv) : 0.f;
    ((float4*)(PL + (size_t)wid * LROW))[lane] = w;
    if (lane == 0) PB[wid] = __expf(row[0] - M) * inv;
}

// ---------------- Phase 2: CTC forward recursion ----------------
// One 64-lane wave per batch element. Lane l holds ext-lattice states
// 8l..8l+7 (L = 401 real states; states > 400 are harmless garbage:
// transitions are non-decreasing in s, so they never flow into s <= 400).
// Linear domain, per-lane power-of-2 scaling via v_ldexp (exact).
// Named-register depth-16 software pipeline: NO arrays -> no scratch (rule #20).

#define STEP(q, qb) do {                                    \
    float sh_  = __shfl_up(a7, 1);                          \
    float prev = ldx(sh_, dB);            /* lane0: dB=-100000 -> 0 */ \
    float n0 = (a0 + prev) * (qb);                          \
    float n1 = fmaf(mk0, prev, a1 + a0) * (q).x;            \
    float n2 = (a2 + a1) * (qb);                            \
    float n3 = fmaf(mk1, a1, a3 + a2) * (q).y;              \
    float n4 = (a4 + a3) * (qb);                            \
    float n5 = fmaf(mk2, a3, a5 + a4) * (q).z;              \
    float n6 = (a6 + a5) * (qb);                            \
    float n7 = fmaf(mk3, a5, a7 + a6) * (q).w;              \
    a0=n0; a1=n1; a2=n2; a3=n3; a4=n4; a5=n5; a6=n6; a7=n7; } while (0)

// every-4-step cadence: worst-case decay 4*2^-21.6 * 2^-30 in-lane range
// = 2^-116 > 2^-126 (f32 normal floor). Every-8 would risk flush-to-zero.
#define RESCALE() do {                                      \
    float mx = fmaxf(fmaxf(fmaxf(a0,a1),fmaxf(a2,a3)),fmaxf(fmaxf(a4,a5),fmaxf(a6,a7))); \
    unsigned eb = (__float_as_uint(mx) >> 23) & 255u;       \
    int de = (eb == 0u) ? 0 : ((int)eb - 127);              \
    a0 = ldx(a0, -de); a1 = ldx(a1, -de); a2 = ldx(a2, -de); a3 = ldx(a3, -de); \
    a4 = ldx(a4, -de); a5 = ldx(a5, -de); a6 = ldx(a6, -de); a7 = ldx(a7, -de); \
    e_acc += de;                                            \
    int she = __shfl_up(e_acc, 1);                          \
    if (eb == 0u) e_acc = she;        /* inactive lane adopts prev's scale */ \
    dB = (lane == 0) ? -100000 : (she - e_acc); } while (0)

// prefetch row `tnext` (clamped) into named regs Q (float4 label probs) / Bv (blank)
#define PF(Q, Bv, tnext) do {                               \
    int tn_ = (tnext); tn_ = (tn_ < Tb) ? tn_ : (Tb - 1);   \
    Q  = ((const float4*)(PLb + (size_t)tn_ * (BB * LROW)))[lane]; \
    Bv = PBb[(size_t)tn_ * BB]; } while (0)

#define UNIT(Q, Bv, i) do { STEP(Q, Bv); if (((i) & 3) == 3) RESCALE(); PF(Q, Bv, t + 16 + (i)); } while (0)
#define TAILU(Q, Bv, i) do { if ((i) < rem) { STEP(Q, Bv); if (((i) & 3) == 3) RESCALE(); } } while (0)

__global__ __launch_bounds__(64, 1) void ctc_phase2(
    const float* __restrict__ PL, const float* __restrict__ PB,
    const int* __restrict__ targets, const int* __restrict__ ilen,
    const int* __restrict__ tlen, float* __restrict__ out)
{
    int b = blockIdx.x;
    int lane = threadIdx.x;
    const int* __restrict__ tg = targets + b * SS;

    // skip masks for odd states s=8l+2c+1 (u=4l+c): allowed when u>=1 && tg[u]!=tg[u-1]
    float mk0 = 0.f, mk1 = 0.f, mk2 = 0.f, mk3 = 0.f;
    {
        int u0 = 4 * lane;
        if (u0 >= 1 && u0 < SS) mk0 = (tg[u0] != tg[u0 - 1]) ? 1.f : 0.f;
        if (u0 + 1 < SS)        mk1 = (tg[u0 + 1] != tg[u0]) ? 1.f : 0.f;
        if (u0 + 2 < SS)        mk2 = (tg[u0 + 2] != tg[u0 + 1]) ? 1.f : 0.f;
        if (u0 + 3 < SS)        mk3 = (tg[u0 + 3] != tg[u0 + 2]) ? 1.f : 0.f;
    }
    int Tb = ilen[b];
    int tl = tlen[b];

    float a0=0,a1=0,a2=0,a3=0,a4=0,a5=0,a6=0,a7=0;
    int e_acc = 0;
    int dB = (lane == 0) ? -100000 : 0;

    const float* __restrict__ PLb = PL + (size_t)b * LROW;
    const float* __restrict__ PBb = PB + b;

    // t = 0 init: alpha[0] = p_blank, alpha[1] = p(tgt[0])
    {
        float4 p0 = ((const float4*)PLb)[lane];
        float pb0 = PBb[0];
        if (lane == 0) { a0 = pb0; a1 = p0.x; }
    }

    int nsteps = Tb - 1;
    float4 q0,q1,q2,q3,q4,q5,q6,q7,q8,q9,q10,q11,q12,q13,q14,q15;
    float  c0,c1,c2,c3,c4,c5,c6,c7,c8,c9,c10,c11,c12,c13,c14,c15;

    PF(q0,c0,1);   PF(q1,c1,2);   PF(q2,c2,3);   PF(q3,c3,4);
    PF(q4,c4,5);   PF(q5,c5,6);   PF(q6,c6,7);   PF(q7,c7,8);
    PF(q8,c8,9);   PF(q9,c9,10);  PF(q10,c10,11); PF(q11,c11,12);
    PF(q12,c12,13); PF(q13,c13,14); PF(q14,c14,15); PF(q15,c15,16);

    int t = 1;
    for (; t + 15 <= nsteps; t += 16) {
        UNIT(q0,c0,0);   UNIT(q1,c1,1);   UNIT(q2,c2,2);   UNIT(q3,c3,3);
        UNIT(q4,c4,4);   UNIT(q5,c5,5);   UNIT(q6,c6,6);   UNIT(q7,c7,7);
        UNIT(q8,c8,8);   UNIT(q9,c9,9);   UNIT(q10,c10,10); UNIT(q11,c11,11);
        UNIT(q12,c12,12); UNIT(q13,c13,13); UNIT(q14,c14,14); UNIT(q15,c15,15);
    }
    int rem = nsteps - t + 1;    // 0..15 remaining; q0..q15 hold rows t..t+15
    TAILU(q0,c0,0);   TAILU(q1,c1,1);   TAILU(q2,c2,2);   TAILU(q3,c3,3);
    TAILU(q4,c4,4);   TAILU(q5,c5,5);   TAILU(q6,c6,6);   TAILU(q7,c7,7);
    TAILU(q8,c8,8);   TAILU(q9,c9,9);   TAILU(q10,c10,10); TAILU(q11,c11,11);
    TAILU(q12,c12,12); TAILU(q13,c13,13); TAILU(q14,c14,14); TAILU(q15,c15,15);

    // readout: loss = -logaddexp(alpha[2*tl], alpha[2*tl-1])
    __shared__ float sa[64][8];
    __shared__ int   se[64];
    sa[lane][0]=a0; sa[lane][1]=a1; sa[lane][2]=a2; sa[lane][3]=a3;
    sa[lane][4]=a4; sa[lane][5]=a5; sa[lane][6]=a6; sa[lane][7]=a7;
    se[lane] = e_acc;
    __syncthreads();
    if (lane == 0) {
        int end = 2 * tl;
        float ae = sa[end >> 3][end & 7];
        float am = sa[(end - 1) >> 3][(end - 1) & 7];
        int   ee = se[end >> 3];
        int   em = se[(end - 1) >> 3];
        float val = ae + ldx(am, em - ee);           // bring to common scale
        double lb = -((double)logf(val) + (double)ee * 0.6931471805599453);
        float contrib = (float)(lb / ((double)tl * (double)BB));
        atomicAdd(out, contrib);
    }
}

extern "C" void kernel_launch(void* const* d_in, const int* in_sizes, int n_in,
                              void* d_out, int out_size, void* d_ws, size_t ws_size,
                              hipStream_t stream)
{
    const float* logits  = (const float*)d_in[0];
    const int*   targets = (const int*)d_in[1];
    const int*   ilen    = (const int*)d_in[2];
    const int*   tlen    = (const int*)d_in[3];
    float* out = (float*)d_out;

    float* PL = (float*)d_ws;                                  // [TT*BB][256] f32
    float* PB = PL + (size_t)TT * BB * LROW;                   // [TT*BB] f32

    ctc_phase1<<<(TT * BB) / 4, 256, 0, stream>>>(logits, targets, PL, PB, out);
    ctc_phase2<<<BB, 64, 0, stream>>>(PL, PB, targets, ilen, tlen, out);
}